// Round 3
// baseline (590.953 us; speedup 1.0000x reference)
//
#include <hip/hip_runtime.h>

// Output: diag(ics_mask - params * r_mask), N x N fp32, N = 12288 (~604 MB).
// Harness poisons d_out to 0xAA before every timed launch -> must rewrite all.
//
// Round-2 lesson: hipMemsetAsync captured into the graph ran at only ~3.4 TB/s
// (graph memset node != the 6.3 TB/s rocclr fillBufferAligned kernel the
// harness's poison uses). So do the fill ourselves, structured to be pure
// streaming dwordx4 stores with zero per-iteration integer division:
//   - one block per row (row = blockIdx.x, an SGPR -> scalar loads for diag)
//   - 256 threads x 12 unrolled float4 stores = 3072 float4 = one 48 KB row
//   - diagonal folded in via (j == row>>2) ? diag_vec : zero  (1 cmp + 4
//     cndmask per 1024B wave-store; VALU ~30x below what's needed at 6.3 TB/s)

#define DIAG_N 12288
#define N4_PER_ROW (DIAG_N / 4)          // 3072 float4 per row
#define THREADS 256
#define F4_PER_THREAD (N4_PER_ROW / THREADS)  // 12

__global__ __launch_bounds__(THREADS) void diag_row_fill(
    const float* __restrict__ params,
    const int*   __restrict__ r_mask,
    const int*   __restrict__ ics_mask,
    float4*      __restrict__ out)
{
    const int row = blockIdx.x;          // wave-uniform -> SGPR
    const int t   = threadIdx.x;

    // Uniform per block: diag value and its position within the row.
    const int   d4   = row >> 2;         // which float4 of this row holds it
    const int   lane = row & 3;          // which component of that float4
    const float d    = (float)ics_mask[row] - params[row] * (float)r_mask[row];

    float4 dv;
    dv.x = (lane == 0) ? d : 0.f;
    dv.y = (lane == 1) ? d : 0.f;
    dv.z = (lane == 2) ? d : 0.f;
    dv.w = (lane == 3) ? d : 0.f;
    const float4 z = make_float4(0.f, 0.f, 0.f, 0.f);

    float4* rowp = out + (size_t)row * N4_PER_ROW;
#pragma unroll
    for (int k = 0; k < F4_PER_THREAD; ++k) {
        const int j = t + k * THREADS;   // coalesced: lane i -> 16B slot i
        rowp[j] = (j == d4) ? dv : z;
    }
}

extern "C" void kernel_launch(void* const* d_in, const int* in_sizes, int n_in,
                              void* d_out, int out_size, void* d_ws, size_t ws_size,
                              hipStream_t stream) {
    const float* params   = (const float*)d_in[0];
    const int*   r_mask   = (const int*)d_in[1];
    const int*   ics_mask = (const int*)d_in[2];
    float4*      out      = (float4*)d_out;

    dim3 grid(DIAG_N), block(THREADS);   // one block per row, 48 blocks/CU
    hipLaunchKernelGGL(diag_row_fill, grid, block, 0, stream,
                       params, r_mask, ics_mask, out);
}